// Round 12
// baseline (199.019 us; speedup 1.0000x reference)
//
#include <hip/hip_runtime.h>
#include <hip/hip_bf16.h>
#include <stdint.h>

typedef short short8 __attribute__((ext_vector_type(8)));
typedef float f32x4 __attribute__((ext_vector_type(4)));

#define BQ 4
#define NSEQ 2048
#define DMODEL 1024
#define NHEAD 16
#define HDIM 64
#define MTOT 8192          // BQ*NSEQ
#define QKV_LD 3072

#if __has_builtin(__builtin_amdgcn_exp2f)
#define EXP2(x) __builtin_amdgcn_exp2f(x)
#else
#define EXP2(x) exp2f(x)
#endif
#define C_SCL 0.18033688f   // 0.125 * log2(e)
#define THR_RAW 16.635532f  // 3.0 / C_SCL : defer-max threshold (P bounded by 2^3)

__device__ __forceinline__ uint16_t f2bf(float f) {
  uint32_t u = __builtin_bit_cast(uint32_t, f);
  uint32_t r = (u + 0x7FFFu + ((u >> 16) & 1u)) >> 16;
  return (uint16_t)r;
}
// hardware RNE convert (v_cvt_pk_bf16_f32 after compiler fusion)
__device__ __forceinline__ uint16_t f2bf_hw(float f) {
  __hip_bfloat16 h = __float2bfloat16(f);
  return __builtin_bit_cast(uint16_t, h);
}

__global__ void cast_f32_bf16_k(const float* __restrict__ in, uint16_t* __restrict__ out, int n) {
  int idx = (blockIdx.x * blockDim.x + threadIdx.x) * 4;
  int stride = gridDim.x * blockDim.x * 4;
  for (int i = idx; i < n; i += stride) {
    float4 v = *reinterpret_cast<const float4*>(in + i);
    ushort4 o;
    o.x = f2bf(v.x); o.y = f2bf(v.y); o.z = f2bf(v.z); o.w = f2bf(v.w);
    *reinterpret_cast<ushort4*>(out + i) = o;
  }
}

// in [K][N] f32 row-major -> out [N][K] bf16 row-major
__global__ void transpose_cast_k(const float* __restrict__ in, uint16_t* __restrict__ out, int K, int N) {
  __shared__ float tile[32][33];
  int n0 = blockIdx.x * 32;
  int k0 = blockIdx.y * 32;
  int tx = threadIdx.x & 31;
  int ty = threadIdx.x >> 5;
#pragma unroll
  for (int r = 0; r < 4; ++r)
    tile[ty + r * 8][tx] = in[(size_t)(k0 + ty + r * 8) * N + n0 + tx];
  __syncthreads();
#pragma unroll
  for (int r = 0; r < 4; ++r)
    out[(size_t)(n0 + ty + r * 8) * K + k0 + tx] = f2bf(tile[tx][ty + r * 8]);
}

// C[M,N] = A[M,K] @ BT[N,K]^T ; A,BT bf16 row-major. 128x128 tile, BK=32.
// Staging via global_load_lds width=16 (m97 structure).
template <bool BF16_OUT>
__global__ void __launch_bounds__(256, 2)
gemm_bt_k(const uint16_t* __restrict__ A, const uint16_t* __restrict__ BT,
          void* __restrict__ Cout, const float* __restrict__ bias,
          int M, int N, int K) {
  __shared__ uint16_t As[128 * 32];
  __shared__ uint16_t Bs[128 * 32];
  const int tid = threadIdx.x;
  const int lane = tid & 63;
  const int wave = tid >> 6;
  const int wr = wave >> 1, wc = wave & 1;   // wave -> 64x64 quadrant
  const int brow = blockIdx.y * 128;
  const int bcol = blockIdx.x * 128;
  const int l16 = lane & 15;
  const int lq = lane >> 4;

  f32x4 acc[4][4];
  const f32x4 fzero = {0.f, 0.f, 0.f, 0.f};
#pragma unroll
  for (int i = 0; i < 4; ++i)
#pragma unroll
    for (int j = 0; j < 4; ++j) acc[i][j] = fzero;

  // staging: 512 16B-chunks per tile; chunk c -> row c>>2, k-off (c&3)*8; LDS linear at c*8 elems
  const int ca = tid, cb = tid + 256;
  const size_t ga0 = (size_t)(brow + (ca >> 2)) * K + (ca & 3) * 8;
  const size_t ga1 = (size_t)(brow + (cb >> 2)) * K + (cb & 3) * 8;
  const size_t gb0 = (size_t)(bcol + (ca >> 2)) * K + (ca & 3) * 8;
  const size_t gb1 = (size_t)(bcol + (cb >> 2)) * K + (cb & 3) * 8;

  for (int kt = 0; kt < K; kt += 32) {
    __builtin_amdgcn_global_load_lds(
        (const __attribute__((address_space(1))) void*)(A + ga0 + kt),
        (__attribute__((address_space(3))) void*)&As[ca * 8], 16, 0, 0);
    __builtin_amdgcn_global_load_lds(
        (const __attribute__((address_space(1))) void*)(A + ga1 + kt),
        (__attribute__((address_space(3))) void*)&As[cb * 8], 16, 0, 0);
    __builtin_amdgcn_global_load_lds(
        (const __attribute__((address_space(1))) void*)(BT + gb0 + kt),
        (__attribute__((address_space(3))) void*)&Bs[ca * 8], 16, 0, 0);
    __builtin_amdgcn_global_load_lds(
        (const __attribute__((address_space(1))) void*)(BT + gb1 + kt),
        (__attribute__((address_space(3))) void*)&Bs[cb * 8], 16, 0, 0);
    __syncthreads();   // implicit vmcnt(0) drain before barrier
    short8 af[4], bfr[4];
#pragma unroll
    for (int r = 0; r < 4; ++r) {
      af[r]  = *reinterpret_cast<const short8*>(&As[(wr * 64 + r * 16 + l16) * 32 + lq * 8]);
      bfr[r] = *reinterpret_cast<const short8*>(&Bs[(wc * 64 + r * 16 + l16) * 32 + lq * 8]);
    }
#pragma unroll
    for (int r = 0; r < 4; ++r)
#pragma unroll
      for (int c = 0; c < 4; ++c)
        acc[r][c] = __builtin_amdgcn_mfma_f32_16x16x32_bf16(af[r], bfr[c], acc[r][c], 0, 0, 0);
    __syncthreads();
  }

#pragma unroll
  for (int r = 0; r < 4; ++r) {
    const int row0 = brow + wr * 64 + r * 16 + lq * 4;
#pragma unroll
    for (int c = 0; c < 4; ++c) {
      const int col = bcol + wc * 64 + c * 16 + l16;
#pragma unroll
      for (int i = 0; i < 4; ++i) {
        if constexpr (BF16_OUT)
          reinterpret_cast<uint16_t*>(Cout)[(size_t)(row0 + i) * N + col] = f2bf(acc[r][c][i]);
        else
          reinterpret_cast<float*>(Cout)[(size_t)(row0 + i) * N + col] = acc[r][c][i] + bias[col];
      }
    }
  }
}

// Flash attention, causal. qkv [MTOT][3072] bf16 (q|k|v), out [MTOT][1024] bf16.
// ROUND-12: double-buffered Ks/Vt -> ONE barrier per KV-iteration (was 2).
//   Safety: buffer jt&1 written in iter jt was last read in iter jt-2; barrier(jt-1)
//   separates them (a wave committing iter jt passed barrier(jt-1); no wave passes
//   barrier(jt-1) before finishing compute(jt-2)).
// T1: XCD swizzle (FETCH 152->24.6 MB measured, K/V L2-resident). T5: setprio on MFMA.
// PAIRED Q-TILES: q-tiles p and 31-p in ONE K/V sweep; flat 33-iter blocks.
// A/B SEQUENTIAL per iter (one sv[4] live). SWAPPED QK^T: lane holds S[k][q=l16].
// P-IN-REGISTER via sigma-permuted V layout (no P LDS round-trip).
// Softmax: hw bf16 cvt, rsum over unrounded f32, T13 defer-max, raw-S exp2-fma.
// K/V async-STAGE (prefetch jt+1 into regs, commit at next iter top).
__global__ void __launch_bounds__(256, 3)
attn_fwd_k(const uint16_t* __restrict__ qkv, uint16_t* __restrict__ outb) {
  const int obid = blockIdx.x;
  const int bid = (obid & 7) * 128 + (obid >> 3);   // T1: contiguous 128-block chunk per XCD
  const int p = bid & 15;
  const int h = (bid >> 4) & 15;
  const int b = bid >> 8;
  const int qtA = p;
  const int qtB = 31 - p;
  const int tid = threadIdx.x;
  const int lane = tid & 63;
  const int w = tid >> 6;
  const int l16 = lane & 15;
  const int lq = lane >> 4;

  __shared__ uint16_t Ks[2][64 * 72];      // [buf][token][d], stride 72
  __shared__ uint16_t Vt[2][64 * 72];      // [buf][d][sigma-permuted token], stride 72

  // Q fragments for both q-tiles (row=l16, k=8*lq+j per 32-d chunk)
  short8 qaA0, qaA1, qaB0, qaB1;
  {
    const size_t baseA = ((size_t)(b * NSEQ + qtA * 64 + w * 16 + l16)) * QKV_LD + h * 64 + lq * 8;
    const size_t baseB = ((size_t)(b * NSEQ + qtB * 64 + w * 16 + l16)) * QKV_LD + h * 64 + lq * 8;
    qaA0 = *reinterpret_cast<const short8*>(qkv + baseA);
    qaA1 = *reinterpret_cast<const short8*>(qkv + baseA + 32);
    qaB0 = *reinterpret_cast<const short8*>(qkv + baseB);
    qaB1 = *reinterpret_cast<const short8*>(qkv + baseB + 32);
  }

  float mA = -1e30f, lA = 0.f, mB = -1e30f, lB = 0.f;
  f32x4 accA[4], accB[4];
  const f32x4 fzero = {0.f, 0.f, 0.f, 0.f};
#pragma unroll
  for (int i = 0; i < 4; ++i) { accA[i] = fzero; accB[i] = fzero; }

  // staging geometry: 512 chunks, chunk c -> token row c>>3, d-off (c&7)*8
  const int r0 = tid >> 3, d0 = (tid & 7) * 8;
  const int ka0 = r0 * 72 + d0;
  const int ka1 = (r0 + 32) * 72 + d0;
  const int lqt = (r0 >> 2) & 3;
  const int nc0 = r0 >> 4;
  const int m0 = d0 >> 3;
  const int jo = (nc0 & 1) * 4 + (r0 & 3);
  const int vcol0 = (((2 * lqt) ^ m0) * 8) + jo;        // token r0  -> pa0 chunk
  const int vcol1 = (((2 * lqt + 1) ^ m0) * 8) + jo;    // token r0+32 -> pa1 chunk

  const int ntiles = qtB + 1;
  short8 rk0, rk1, rv0, rv1;
  {
    const size_t g0 = ((size_t)(b * NSEQ + r0)) * QKV_LD + 1024 + h * 64 + d0;
    const size_t g1 = ((size_t)(b * NSEQ + r0 + 32)) * QKV_LD + 1024 + h * 64 + d0;
    rk0 = *reinterpret_cast<const short8*>(qkv + g0);
    rv0 = *reinterpret_cast<const short8*>(qkv + g0 + 1024);
    rk1 = *reinterpret_cast<const short8*>(qkv + g1);
    rv1 = *reinterpret_cast<const short8*>(qkv + g1 + 1024);
  }

// ksb/vtb: current-iteration LDS buffer pointers (declared in the loop)
#define SOFTMAX_PV(SV, M_I, L_I, ACC, DIAG)                                     \
  {                                                                             \
    float tmax_ = -3e38f;                                                       \
    _Pragma("unroll") for (int nc = 0; nc < 4; ++nc) {                          \
      _Pragma("unroll") for (int i = 0; i < 4; ++i) {                           \
        float v_ = SV[nc][i];                                                   \
        if ((DIAG) && (nc * 16 + lq * 4 + i) > (w * 16 + l16)) v_ = -3e38f;     \
        SV[nc][i] = v_;                                                         \
        tmax_ = fmaxf(tmax_, v_);                                               \
      }                                                                         \
    }                                                                           \
    tmax_ = fmaxf(tmax_, __shfl_xor(tmax_, 16, 64));                            \
    tmax_ = fmaxf(tmax_, __shfl_xor(tmax_, 32, 64));                            \
    if (!__all(tmax_ <= M_I + THR_RAW)) {                                       \
      const float mn_ = fmaxf(M_I, tmax_);                                      \
      const float alpha_ = EXP2((M_I - mn_) * C_SCL);                           \
      M_I = mn_;                                                                \
      L_I *= alpha_;                                                            \
      float ab_[4];                                                             \
      _Pragma("unroll") for (int i = 0; i < 4; ++i)                             \
        ab_[i] = __shfl(alpha_, lq * 4 + i, 64);                                \
      _Pragma("unroll") for (int d4 = 0; d4 < 4; ++d4)                          \
        _Pragma("unroll") for (int i = 0; i < 4; ++i)                           \
          ACC[d4][i] *= ab_[i];                                                 \
    }                                                                           \
    const float mc_ = M_I * C_SCL;                                              \
    float rsum_ = 0.f;                                                          \
    short8 pa0_, pa1_;                                                          \
    _Pragma("unroll") for (int nc = 0; nc < 4; ++nc) {                          \
      _Pragma("unroll") for (int i = 0; i < 4; ++i) {                           \
        float pv_ = EXP2(__builtin_fmaf(SV[nc][i], C_SCL, -mc_));               \
        rsum_ += pv_;                                                           \
        uint16_t ph_ = f2bf_hw(pv_);                                            \
        if (nc < 2) pa0_[nc * 4 + i] = (short)ph_;                              \
        else        pa1_[(nc - 2) * 4 + i] = (short)ph_;                        \
      }                                                                         \
    }                                                                           \
    rsum_ += __shfl_xor(rsum_, 16, 64);                                         \
    rsum_ += __shfl_xor(rsum_, 32, 64);                                         \
    L_I += rsum_;                                                               \
    __builtin_amdgcn_s_setprio(1);                                              \
    _Pragma("unroll") for (int d4 = 0; d4 < 4; ++d4) {                          \
      const int drow_ = d4 * 16 + l16;                                          \
      const int xr_ = (drow_ >> 3) & 7;                                         \
      short8 vb0_ = *reinterpret_cast<const short8*>(&vtb[drow_ * 72 + (((2 * lq) ^ xr_) * 8)]); \
      short8 vb1_ = *reinterpret_cast<const short8*>(&vtb[drow_ * 72 + (((2 * lq + 1) ^ xr_) * 8)]); \
      ACC[d4] = __builtin_amdgcn_mfma_f32_16x16x32_bf16(pa0_, vb0_, ACC[d4], 0, 0, 0); \
      ACC[d4] = __builtin_amdgcn_mfma_f32_16x16x32_bf16(pa1_, vb1_, ACC[d4], 0, 0, 0); \
    }                                                                           \
    __builtin_amdgcn_s_setprio(0);                                              \
  }

  for (int jt = 0; jt < ntiles; ++jt) {
    uint16_t* ksb = Ks[jt & 1];
    uint16_t* vtb = Vt[jt & 1];
    // --- commit staged regs to this iter's buffer (other buffer still in use last iter;
    //     this buffer's last readers finished before barrier(jt-1)) ---
    *reinterpret_cast<short8*>(&ksb[ka0]) = rk0;
    *reinterpret_cast<short8*>(&ksb[ka1]) = rk1;
#pragma unroll
    for (int j = 0; j < 8; ++j) vtb[(d0 + j) * 72 + vcol0] = (uint16_t)rv0[j];
#pragma unroll
    for (int j = 0; j < 8; ++j) vtb[(d0 + j) * 72 + vcol1] = (uint16_t)rv1[j];
    // --- issue next tile's global loads; latency hides under this tile's compute ---
    if (jt + 1 < ntiles) {
      const size_t g0 = ((size_t)(b * NSEQ + (jt + 1) * 64 + r0)) * QKV_LD + 1024 + h * 64 + d0;
      const size_t g1 = ((size_t)(b * NSEQ + (jt + 1) * 64 + r0 + 32)) * QKV_LD + 1024 + h * 64 + d0;
      rk0 = *reinterpret_cast<const short8*>(qkv + g0);
      rv0 = *reinterpret_cast<const short8*>(qkv + g0 + 1024);
      rk1 = *reinterpret_cast<const short8*>(qkv + g1);
      rv1 = *reinterpret_cast<const short8*>(qkv + g1 + 1024);
    }
    __syncthreads();   // the ONLY barrier this iteration

    // --- tile B: S^T = K Q^T, softmax, PV ---
    {
      f32x4 sv[4];
      __builtin_amdgcn_s_setprio(1);
#pragma unroll
      for (int nc = 0; nc < 4; ++nc) {
        short8 kb0 = *reinterpret_cast<const short8*>(&ksb[(nc * 16 + l16) * 72 + lq * 8]);
        short8 kb1 = *reinterpret_cast<const short8*>(&ksb[(nc * 16 + l16) * 72 + 32 + lq * 8]);
        f32x4 s = fzero;
        s = __builtin_amdgcn_mfma_f32_16x16x32_bf16(kb0, qaB0, s, 0, 0, 0);
        s = __builtin_amdgcn_mfma_f32_16x16x32_bf16(kb1, qaB1, s, 0, 0, 0);
        sv[nc] = s;
      }
      __builtin_amdgcn_s_setprio(0);
      SOFTMAX_PV(sv, mB, lB, accB, jt == qtB);
    }

    // --- tile A (active while jt <= qtA) ---
    if (jt <= qtA) {
      f32x4 sv[4];
      __builtin_amdgcn_s_setprio(1);
#pragma unroll
      for (int nc = 0; nc < 4; ++nc) {
        short8 kb0 = *reinterpret_cast<const short8*>(&ksb[(nc * 16 + l16) * 72 + lq * 8]);
        short8 kb1 = *reinterpret_cast<const short8*>(&ksb[(nc * 16 + l16) * 72 + 32 + lq * 8]);
        f32x4 s = fzero;
        s = __builtin_amdgcn_mfma_f32_16x16x32_bf16(kb0, qaA0, s, 0, 0, 0);
        s = __builtin_amdgcn_mfma_f32_16x16x32_bf16(kb1, qaA1, s, 0, 0, 0);
        sv[nc] = s;
      }
      __builtin_amdgcn_s_setprio(0);
      SOFTMAX_PV(sv, mA, lA, accA, jt == qtA);
    }
    // no trailing barrier: next iter writes the other buffer
  }

  // epilogue: l for acc row q = lq*4 + i lives at lane l16 = q
  {
    float lb4[4];
#pragma unroll
    for (int i = 0; i < 4; ++i) lb4[i] = __shfl(lA, lq * 4 + i, 64);
    const size_t orow = (size_t)(b * NSEQ) + qtA * 64 + w * 16 + lq * 4;
#pragma unroll
    for (int d4 = 0; d4 < 4; ++d4)
#pragma unroll
      for (int i = 0; i < 4; ++i)
        outb[(orow + i) * (size_t)DMODEL + h * 64 + d4 * 16 + l16] = f2bf(accA[d4][i] / lb4[i]);
  }
  {
    float lb4[4];
#pragma unroll
    for (int i = 0; i < 4; ++i) lb4[i] = __shfl(lB, lq * 4 + i, 64);
    const size_t orow = (size_t)(b * NSEQ) + qtB * 64 + w * 16 + lq * 4;
#pragma unroll
    for (int d4 = 0; d4 < 4; ++d4)
#pragma unroll
      for (int i = 0; i < 4; ++i)
        outb[(orow + i) * (size_t)DMODEL + h * 64 + d4 * 16 + l16] = f2bf(accB[d4][i] / lb4[i]);
  }
}

extern "C" void kernel_launch(void* const* d_in, const int* in_sizes, int n_in,
                              void* d_out, int out_size, void* d_ws, size_t ws_size,
                              hipStream_t stream) {
  const float* x      = (const float*)d_in[0];
  const float* w_attn = (const float*)d_in[1];
  const float* w_proj = (const float*)d_in[2];
  const float* b_proj = (const float*)d_in[3];

  uint16_t* xb    = (uint16_t*)d_ws;                    // [8192][1024]
  uint16_t* wat   = xb   + (size_t)MTOT * DMODEL;       // [3072][1024] (w_attn^T)
  uint16_t* wpt   = wat  + (size_t)3072 * 1024;         // [1024][1024] (w_proj^T)
  uint16_t* qkvb  = wpt  + (size_t)1024 * 1024;         // [8192][3072]
  uint16_t* attnb = qkvb + (size_t)MTOT * QKV_LD;       // [8192][1024]

  cast_f32_bf16_k<<<2048, 256, 0, stream>>>(x, xb, MTOT * DMODEL);
  transpose_cast_k<<<dim3(3072 / 32, 1024 / 32), 256, 0, stream>>>(w_attn, wat, 1024, 3072);
  transpose_cast_k<<<dim3(1024 / 32, 1024 / 32), 256, 0, stream>>>(w_proj, wpt, 1024, 1024);

  gemm_bt_k<true><<<dim3(3072 / 128, MTOT / 128), 256, 0, stream>>>(
      xb, wat, qkvb, nullptr, MTOT, 3072, 1024);

  attn_fwd_k<<<BQ * NHEAD * 16, 256, 0, stream>>>(qkvb, attnb);

  gemm_bt_k<false><<<dim3(1024 / 128, MTOT / 128), 256, 0, stream>>>(
      attnb, wpt, d_out, b_proj, MTOT, 1024, 1024);
}

// Round 13
// 188.257 us; speedup vs baseline: 1.0572x; 1.0572x over previous
//
#include <hip/hip_runtime.h>
#include <hip/hip_bf16.h>
#include <stdint.h>

typedef short short8 __attribute__((ext_vector_type(8)));
typedef float f32x4 __attribute__((ext_vector_type(4)));

#define BQ 4
#define NSEQ 2048
#define DMODEL 1024
#define NHEAD 16
#define HDIM 64
#define MTOT 8192          // BQ*NSEQ
#define QKV_LD 3072

#if __has_builtin(__builtin_amdgcn_exp2f)
#define EXP2(x) __builtin_amdgcn_exp2f(x)
#else
#define EXP2(x) exp2f(x)
#endif
#define C_SCL 0.18033688f   // 0.125 * log2(e)
#define THR_RAW 16.635532f  // 3.0 / C_SCL : defer-max threshold (P bounded by 2^3)

__device__ __forceinline__ uint16_t f2bf(float f) {
  uint32_t u = __builtin_bit_cast(uint32_t, f);
  uint32_t r = (u + 0x7FFFu + ((u >> 16) & 1u)) >> 16;
  return (uint16_t)r;
}
// hardware RNE convert (v_cvt_pk_bf16_f32 after compiler fusion)
__device__ __forceinline__ uint16_t f2bf_hw(float f) {
  __hip_bfloat16 h = __float2bfloat16(f);
  return __builtin_bit_cast(uint16_t, h);
}

__global__ void cast_f32_bf16_k(const float* __restrict__ in, uint16_t* __restrict__ out, int n) {
  int idx = (blockIdx.x * blockDim.x + threadIdx.x) * 4;
  int stride = gridDim.x * blockDim.x * 4;
  for (int i = idx; i < n; i += stride) {
    float4 v = *reinterpret_cast<const float4*>(in + i);
    ushort4 o;
    o.x = f2bf(v.x); o.y = f2bf(v.y); o.z = f2bf(v.z); o.w = f2bf(v.w);
    *reinterpret_cast<ushort4*>(out + i) = o;
  }
}

// in [K][N] f32 row-major -> out [N][K] bf16 row-major
__global__ void transpose_cast_k(const float* __restrict__ in, uint16_t* __restrict__ out, int K, int N) {
  __shared__ float tile[32][33];
  int n0 = blockIdx.x * 32;
  int k0 = blockIdx.y * 32;
  int tx = threadIdx.x & 31;
  int ty = threadIdx.x >> 5;
#pragma unroll
  for (int r = 0; r < 4; ++r)
    tile[ty + r * 8][tx] = in[(size_t)(k0 + ty + r * 8) * N + n0 + tx];
  __syncthreads();
#pragma unroll
  for (int r = 0; r < 4; ++r)
    out[(size_t)(n0 + ty + r * 8) * K + k0 + tx] = f2bf(tile[tx][ty + r * 8]);
}

// C[M,N] = A[M,K] @ BT[N,K]^T ; A,BT bf16 row-major. 128x128 tile, BK=32.
// Staging via global_load_lds width=16 (m97 structure).
template <bool BF16_OUT>
__global__ void __launch_bounds__(256, 2)
gemm_bt_k(const uint16_t* __restrict__ A, const uint16_t* __restrict__ BT,
          void* __restrict__ Cout, const float* __restrict__ bias,
          int M, int N, int K) {
  __shared__ uint16_t As[128 * 32];
  __shared__ uint16_t Bs[128 * 32];
  const int tid = threadIdx.x;
  const int lane = tid & 63;
  const int wave = tid >> 6;
  const int wr = wave >> 1, wc = wave & 1;   // wave -> 64x64 quadrant
  const int brow = blockIdx.y * 128;
  const int bcol = blockIdx.x * 128;
  const int l16 = lane & 15;
  const int lq = lane >> 4;

  f32x4 acc[4][4];
  const f32x4 fzero = {0.f, 0.f, 0.f, 0.f};
#pragma unroll
  for (int i = 0; i < 4; ++i)
#pragma unroll
    for (int j = 0; j < 4; ++j) acc[i][j] = fzero;

  // staging: 512 16B-chunks per tile; chunk c -> row c>>2, k-off (c&3)*8; LDS linear at c*8 elems
  const int ca = tid, cb = tid + 256;
  const size_t ga0 = (size_t)(brow + (ca >> 2)) * K + (ca & 3) * 8;
  const size_t ga1 = (size_t)(brow + (cb >> 2)) * K + (cb & 3) * 8;
  const size_t gb0 = (size_t)(bcol + (ca >> 2)) * K + (ca & 3) * 8;
  const size_t gb1 = (size_t)(bcol + (cb >> 2)) * K + (cb & 3) * 8;

  for (int kt = 0; kt < K; kt += 32) {
    __builtin_amdgcn_global_load_lds(
        (const __attribute__((address_space(1))) void*)(A + ga0 + kt),
        (__attribute__((address_space(3))) void*)&As[ca * 8], 16, 0, 0);
    __builtin_amdgcn_global_load_lds(
        (const __attribute__((address_space(1))) void*)(A + ga1 + kt),
        (__attribute__((address_space(3))) void*)&As[cb * 8], 16, 0, 0);
    __builtin_amdgcn_global_load_lds(
        (const __attribute__((address_space(1))) void*)(BT + gb0 + kt),
        (__attribute__((address_space(3))) void*)&Bs[ca * 8], 16, 0, 0);
    __builtin_amdgcn_global_load_lds(
        (const __attribute__((address_space(1))) void*)(BT + gb1 + kt),
        (__attribute__((address_space(3))) void*)&Bs[cb * 8], 16, 0, 0);
    __syncthreads();   // implicit vmcnt(0) drain before barrier
    short8 af[4], bfr[4];
#pragma unroll
    for (int r = 0; r < 4; ++r) {
      af[r]  = *reinterpret_cast<const short8*>(&As[(wr * 64 + r * 16 + l16) * 32 + lq * 8]);
      bfr[r] = *reinterpret_cast<const short8*>(&Bs[(wc * 64 + r * 16 + l16) * 32 + lq * 8]);
    }
#pragma unroll
    for (int r = 0; r < 4; ++r)
#pragma unroll
      for (int c = 0; c < 4; ++c)
        acc[r][c] = __builtin_amdgcn_mfma_f32_16x16x32_bf16(af[r], bfr[c], acc[r][c], 0, 0, 0);
    __syncthreads();
  }

#pragma unroll
  for (int r = 0; r < 4; ++r) {
    const int row0 = brow + wr * 64 + r * 16 + lq * 4;
#pragma unroll
    for (int c = 0; c < 4; ++c) {
      const int col = bcol + wc * 64 + c * 16 + l16;
#pragma unroll
      for (int i = 0; i < 4; ++i) {
        if constexpr (BF16_OUT)
          reinterpret_cast<uint16_t*>(Cout)[(size_t)(row0 + i) * N + col] = f2bf(acc[r][c][i]);
        else
          reinterpret_cast<float*>(Cout)[(size_t)(row0 + i) * N + col] = acc[r][c][i] + bias[col];
      }
    }
  }
}

// Flash attention, causal. qkv [MTOT][3072] bf16 (q|k|v), out [MTOT][1024] bf16.
// ROUND-13: revert to round-9 structure (single-buffer Ks/Vt, 2 barriers/iter — the
// best measured: 84.5us attn). R12 dbuf (+12us) and R11 setprio (~+2.5us) removed.
// Kept: T1 XCD swizzle (FETCH 152->24.6 MB, time-neutral).
// NEW: uniform-DIAG branch — jt==qt is wave-uniform; the non-diag path (31/33 of
// calls) skips per-element mask cmp+cndmask+rewrite (~48 VALU ops) and reduces max
// via nested fmax (fuses to v_max3). Attn is softmax-VALU-bound (R10/R11/R12
// eliminated LDS/HBM/barrier theories), so VALU cuts are the lever.
// PAIRED Q-TILES: q-tiles p and 31-p in ONE K/V sweep; flat 33-iter blocks.
// A/B SEQUENTIAL per iter (one sv[4] live). SWAPPED QK^T: lane holds S[k][q=l16].
// P-IN-REGISTER via sigma-permuted V layout (no P LDS round-trip).
// Softmax: hw bf16 cvt, rsum over unrounded f32, T13 defer-max, raw-S exp2-fma.
// K/V async-STAGE (prefetch jt+1 into regs, commit after loop-end barrier).
__global__ void __launch_bounds__(256, 3)
attn_fwd_k(const uint16_t* __restrict__ qkv, uint16_t* __restrict__ outb) {
  const int obid = blockIdx.x;
  const int bid = (obid & 7) * 128 + (obid >> 3);   // T1: contiguous 128-block chunk per XCD
  const int p = bid & 15;
  const int h = (bid >> 4) & 15;
  const int b = bid >> 8;
  const int qtA = p;
  const int qtB = 31 - p;
  const int tid = threadIdx.x;
  const int lane = tid & 63;
  const int w = tid >> 6;
  const int l16 = lane & 15;
  const int lq = lane >> 4;

  __shared__ uint16_t Ks[64 * 72];         // [token][d], stride 72
  __shared__ uint16_t Vt[64 * 72];         // [d][sigma-permuted token], stride 72

  // Q fragments for both q-tiles (row=l16, k=8*lq+j per 32-d chunk)
  short8 qaA0, qaA1, qaB0, qaB1;
  {
    const size_t baseA = ((size_t)(b * NSEQ + qtA * 64 + w * 16 + l16)) * QKV_LD + h * 64 + lq * 8;
    const size_t baseB = ((size_t)(b * NSEQ + qtB * 64 + w * 16 + l16)) * QKV_LD + h * 64 + lq * 8;
    qaA0 = *reinterpret_cast<const short8*>(qkv + baseA);
    qaA1 = *reinterpret_cast<const short8*>(qkv + baseA + 32);
    qaB0 = *reinterpret_cast<const short8*>(qkv + baseB);
    qaB1 = *reinterpret_cast<const short8*>(qkv + baseB + 32);
  }

  float mA = -1e30f, lA = 0.f, mB = -1e30f, lB = 0.f;
  f32x4 accA[4], accB[4];
  const f32x4 fzero = {0.f, 0.f, 0.f, 0.f};
#pragma unroll
  for (int i = 0; i < 4; ++i) { accA[i] = fzero; accB[i] = fzero; }

  // staging geometry: 512 chunks, chunk c -> token row c>>3, d-off (c&7)*8
  const int r0 = tid >> 3, d0 = (tid & 7) * 8;
  const int ka0 = r0 * 72 + d0;
  const int ka1 = (r0 + 32) * 72 + d0;
  const int lqt = (r0 >> 2) & 3;
  const int nc0 = r0 >> 4;
  const int m0 = d0 >> 3;
  const int jo = (nc0 & 1) * 4 + (r0 & 3);
  const int vcol0 = (((2 * lqt) ^ m0) * 8) + jo;        // token r0  -> pa0 chunk
  const int vcol1 = (((2 * lqt + 1) ^ m0) * 8) + jo;    // token r0+32 -> pa1 chunk

  const int ntiles = qtB + 1;
  short8 rk0, rk1, rv0, rv1;
  {
    const size_t g0 = ((size_t)(b * NSEQ + r0)) * QKV_LD + 1024 + h * 64 + d0;
    const size_t g1 = ((size_t)(b * NSEQ + r0 + 32)) * QKV_LD + 1024 + h * 64 + d0;
    rk0 = *reinterpret_cast<const short8*>(qkv + g0);
    rv0 = *reinterpret_cast<const short8*>(qkv + g0 + 1024);
    rk1 = *reinterpret_cast<const short8*>(qkv + g1);
    rv1 = *reinterpret_cast<const short8*>(qkv + g1 + 1024);
  }

#define SOFTMAX_PV(SV, M_I, L_I, ACC, DIAG)                                     \
  {                                                                             \
    float tmax_ = -3e38f;                                                       \
    if (DIAG) {                                                                 \
      _Pragma("unroll") for (int nc = 0; nc < 4; ++nc) {                        \
        _Pragma("unroll") for (int i = 0; i < 4; ++i) {                         \
          float v_ = SV[nc][i];                                                 \
          if ((nc * 16 + lq * 4 + i) > (w * 16 + l16)) v_ = -3e38f;             \
          SV[nc][i] = v_;                                                       \
          tmax_ = fmaxf(tmax_, v_);                                             \
        }                                                                       \
      }                                                                         \
    } else {                                                                    \
      _Pragma("unroll") for (int nc = 0; nc < 4; ++nc)                          \
        tmax_ = fmaxf(tmax_, fmaxf(fmaxf(SV[nc][0], SV[nc][1]),                 \
                                   fmaxf(SV[nc][2], SV[nc][3])));               \
    }                                                                           \
    tmax_ = fmaxf(tmax_, __shfl_xor(tmax_, 16, 64));                            \
    tmax_ = fmaxf(tmax_, __shfl_xor(tmax_, 32, 64));                            \
    if (!__all(tmax_ <= M_I + THR_RAW)) {                                       \
      const float mn_ = fmaxf(M_I, tmax_);                                      \
      const float alpha_ = EXP2((M_I - mn_) * C_SCL);                           \
      M_I = mn_;                                                                \
      L_I *= alpha_;                                                            \
      float ab_[4];                                                             \
      _Pragma("unroll") for (int i = 0; i < 4; ++i)                             \
        ab_[i] = __shfl(alpha_, lq * 4 + i, 64);                                \
      _Pragma("unroll") for (int d4 = 0; d4 < 4; ++d4)                          \
        _Pragma("unroll") for (int i = 0; i < 4; ++i)                           \
          ACC[d4][i] *= ab_[i];                                                 \
    }                                                                           \
    const float mc_ = M_I * C_SCL;                                              \
    float rsum_ = 0.f;                                                          \
    short8 pa0_, pa1_;                                                          \
    _Pragma("unroll") for (int nc = 0; nc < 4; ++nc) {                          \
      _Pragma("unroll") for (int i = 0; i < 4; ++i) {                           \
        float pv_ = EXP2(__builtin_fmaf(SV[nc][i], C_SCL, -mc_));               \
        rsum_ += pv_;                                                           \
        uint16_t ph_ = f2bf_hw(pv_);                                            \
        if (nc < 2) pa0_[nc * 4 + i] = (short)ph_;                              \
        else        pa1_[(nc - 2) * 4 + i] = (short)ph_;                        \
      }                                                                         \
    }                                                                           \
    rsum_ += __shfl_xor(rsum_, 16, 64);                                         \
    rsum_ += __shfl_xor(rsum_, 32, 64);                                         \
    L_I += rsum_;                                                               \
    _Pragma("unroll") for (int d4 = 0; d4 < 4; ++d4) {                          \
      const int drow_ = d4 * 16 + l16;                                          \
      const int xr_ = (drow_ >> 3) & 7;                                         \
      short8 vb0_ = *reinterpret_cast<const short8*>(&Vt[drow_ * 72 + (((2 * lq) ^ xr_) * 8)]); \
      short8 vb1_ = *reinterpret_cast<const short8*>(&Vt[drow_ * 72 + (((2 * lq + 1) ^ xr_) * 8)]); \
      ACC[d4] = __builtin_amdgcn_mfma_f32_16x16x32_bf16(pa0_, vb0_, ACC[d4], 0, 0, 0); \
      ACC[d4] = __builtin_amdgcn_mfma_f32_16x16x32_bf16(pa1_, vb1_, ACC[d4], 0, 0, 0); \
    }                                                                           \
  }

  for (int jt = 0; jt < ntiles; ++jt) {
    // --- commit staged regs to LDS (prev compute finished at loop-end barrier) ---
    *reinterpret_cast<short8*>(&Ks[ka0]) = rk0;
    *reinterpret_cast<short8*>(&Ks[ka1]) = rk1;
#pragma unroll
    for (int j = 0; j < 8; ++j) Vt[(d0 + j) * 72 + vcol0] = (uint16_t)rv0[j];
#pragma unroll
    for (int j = 0; j < 8; ++j) Vt[(d0 + j) * 72 + vcol1] = (uint16_t)rv1[j];
    // --- issue next tile's global loads; latency hides under this tile's compute ---
    if (jt + 1 < ntiles) {
      const size_t g0 = ((size_t)(b * NSEQ + (jt + 1) * 64 + r0)) * QKV_LD + 1024 + h * 64 + d0;
      const size_t g1 = ((size_t)(b * NSEQ + (jt + 1) * 64 + r0 + 32)) * QKV_LD + 1024 + h * 64 + d0;
      rk0 = *reinterpret_cast<const short8*>(qkv + g0);
      rv0 = *reinterpret_cast<const short8*>(qkv + g0 + 1024);
      rk1 = *reinterpret_cast<const short8*>(qkv + g1);
      rv1 = *reinterpret_cast<const short8*>(qkv + g1 + 1024);
    }
    __syncthreads();

    // --- tile B: S^T = K Q^T, softmax, PV ---
    {
      f32x4 sv[4];
#pragma unroll
      for (int nc = 0; nc < 4; ++nc) {
        short8 kb0 = *reinterpret_cast<const short8*>(&Ks[(nc * 16 + l16) * 72 + lq * 8]);
        short8 kb1 = *reinterpret_cast<const short8*>(&Ks[(nc * 16 + l16) * 72 + 32 + lq * 8]);
        f32x4 s = fzero;
        s = __builtin_amdgcn_mfma_f32_16x16x32_bf16(kb0, qaB0, s, 0, 0, 0);
        s = __builtin_amdgcn_mfma_f32_16x16x32_bf16(kb1, qaB1, s, 0, 0, 0);
        sv[nc] = s;
      }
      SOFTMAX_PV(sv, mB, lB, accB, jt == qtB);
    }

    // --- tile A (active while jt <= qtA) ---
    if (jt <= qtA) {
      f32x4 sv[4];
#pragma unroll
      for (int nc = 0; nc < 4; ++nc) {
        short8 kb0 = *reinterpret_cast<const short8*>(&Ks[(nc * 16 + l16) * 72 + lq * 8]);
        short8 kb1 = *reinterpret_cast<const short8*>(&Ks[(nc * 16 + l16) * 72 + 32 + lq * 8]);
        f32x4 s = fzero;
        s = __builtin_amdgcn_mfma_f32_16x16x32_bf16(kb0, qaA0, s, 0, 0, 0);
        s = __builtin_amdgcn_mfma_f32_16x16x32_bf16(kb1, qaA1, s, 0, 0, 0);
        sv[nc] = s;
      }
      SOFTMAX_PV(sv, mA, lA, accA, jt == qtA);
    }

    __syncthreads();   // protect Ks/Vt before next stage-commit
  }

  // epilogue: l for acc row q = lq*4 + i lives at lane l16 = q
  {
    float lb4[4];
#pragma unroll
    for (int i = 0; i < 4; ++i) lb4[i] = __shfl(lA, lq * 4 + i, 64);
    const size_t orow = (size_t)(b * NSEQ) + qtA * 64 + w * 16 + lq * 4;
#pragma unroll
    for (int d4 = 0; d4 < 4; ++d4)
#pragma unroll
      for (int i = 0; i < 4; ++i)
        outb[(orow + i) * (size_t)DMODEL + h * 64 + d4 * 16 + l16] = f2bf(accA[d4][i] / lb4[i]);
  }
  {
    float lb4[4];
#pragma unroll
    for (int i = 0; i < 4; ++i) lb4[i] = __shfl(lB, lq * 4 + i, 64);
    const size_t orow = (size_t)(b * NSEQ) + qtB * 64 + w * 16 + lq * 4;
#pragma unroll
    for (int d4 = 0; d4 < 4; ++d4)
#pragma unroll
      for (int i = 0; i < 4; ++i)
        outb[(orow + i) * (size_t)DMODEL + h * 64 + d4 * 16 + l16] = f2bf(accB[d4][i] / lb4[i]);
  }
}

extern "C" void kernel_launch(void* const* d_in, const int* in_sizes, int n_in,
                              void* d_out, int out_size, void* d_ws, size_t ws_size,
                              hipStream_t stream) {
  const float* x      = (const float*)d_in[0];
  const float* w_attn = (const float*)d_in[1];
  const float* w_proj = (const float*)d_in[2];
  const float* b_proj = (const float*)d_in[3];

  uint16_t* xb    = (uint16_t*)d_ws;                    // [8192][1024]
  uint16_t* wat   = xb   + (size_t)MTOT * DMODEL;       // [3072][1024] (w_attn^T)
  uint16_t* wpt   = wat  + (size_t)3072 * 1024;         // [1024][1024] (w_proj^T)
  uint16_t* qkvb  = wpt  + (size_t)1024 * 1024;         // [8192][3072]
  uint16_t* attnb = qkvb + (size_t)MTOT * QKV_LD;       // [8192][1024]

  cast_f32_bf16_k<<<2048, 256, 0, stream>>>(x, xb, MTOT * DMODEL);
  transpose_cast_k<<<dim3(3072 / 32, 1024 / 32), 256, 0, stream>>>(w_attn, wat, 1024, 3072);
  transpose_cast_k<<<dim3(1024 / 32, 1024 / 32), 256, 0, stream>>>(w_proj, wpt, 1024, 1024);

  gemm_bt_k<true><<<dim3(3072 / 128, MTOT / 128), 256, 0, stream>>>(
      xb, wat, qkvb, nullptr, MTOT, 3072, 1024);

  attn_fwd_k<<<BQ * NHEAD * 16, 256, 0, stream>>>(qkvb, attnb);

  gemm_bt_k<false><<<dim3(1024 / 128, MTOT / 128), 256, 0, stream>>>(
      attnb, wpt, d_out, b_proj, MTOT, 1024, 1024);
}